// Round 1
// baseline (588.008 us; speedup 1.0000x reference)
//
#include <hip/hip_runtime.h>

// Problem constants (match reference)
constexpr int S_ = 200000;   // master nodes
constexpr int N_ = 250000;   // new nodes
// L = B = 64

constexpr int ENC_GRID = 512;
constexpr int NCHUNK   = (N_ + 63) / 64;   // 3907

// ---------------------------------------------------------------------------
// K1: added[n] = (nn_m[nn_n[n]] != n); c_m histogram (added only, over nn_n);
//     cnt histogram (all masters, over nn_m) for CSR.
__global__ void k_added_counts(const int* __restrict__ nn_n, const int* __restrict__ nn_m,
                               int* __restrict__ added, int* __restrict__ c_m,
                               int* __restrict__ cnt) {
    int i = blockIdx.x * 256 + threadIdx.x;
    if (i < N_) {
        int m = nn_n[i];
        int a = (nn_m[m] != i) ? 1 : 0;
        added[i] = a;
        if (a) atomicAdd(&c_m[m], 1);
    }
    if (i < S_) {
        atomicAdd(&cnt[nn_m[i]], 1);
    }
}

// ---------------------------------------------------------------------------
// K2: per-block sums of cnt (1024 elements / block) for the exclusive scan.
__global__ void k_scan_blocksum(const int* __restrict__ cnt, int* __restrict__ bsum) {
    __shared__ int sd[256];
    int b = blockIdx.x, t = threadIdx.x;
    int base = b * 1024 + t * 4;
    int s = 0;
#pragma unroll
    for (int k = 0; k < 4; k++) { int idx = base + k; if (idx < N_) s += cnt[idx]; }
    sd[t] = s;
    __syncthreads();
    for (int off = 128; off > 0; off >>= 1) {
        if (t < off) sd[t] += sd[t + off];
        __syncthreads();
    }
    if (t == 0) bsum[b] = sd[0];
}

// K3: exclusive scan -> offs. Each block re-sums previous block sums (<=245).
__global__ void k_scan_apply(const int* __restrict__ cnt, const int* __restrict__ bsum,
                             int* __restrict__ offs) {
    __shared__ int sd[256];
    __shared__ int sp[256];
    int b = blockIdx.x, t = threadIdx.x;
    sp[t] = (t < b) ? bsum[t] : 0;
    __syncthreads();
    for (int off = 128; off > 0; off >>= 1) {
        if (t < off) sp[t] += sp[t + off];
        __syncthreads();
    }
    int prev = sp[0];

    int base = b * 1024 + t * 4;
    int v[4]; int s = 0;
#pragma unroll
    for (int k = 0; k < 4; k++) { int idx = base + k; v[k] = (idx < N_) ? cnt[idx] : 0; s += v[k]; }
    sd[t] = s;
    __syncthreads();
    for (int off = 1; off < 256; off <<= 1) {
        int xv = (t >= off) ? sd[t - off] : 0;
        __syncthreads();
        sd[t] += xv;
        __syncthreads();
    }
    int run = prev + sd[t] - s;
#pragma unroll
    for (int k = 0; k < 4; k++) {
        int idx = base + k;
        if (idx < N_) offs[idx] = run;
        run += v[k];
    }
}

// K4: CSR fill — list of masters per new-node segment.
__global__ void k_fill(const int* __restrict__ nn_m, const int* __restrict__ offs,
                       int* __restrict__ fill, int* __restrict__ list) {
    int m = blockIdx.x * 256 + threadIdx.x;
    if (m < S_) {
        int j = nn_m[m];
        int p = atomicAdd(&fill[j], 1);
        list[offs[j] + p] = m;
    }
}

// ---------------------------------------------------------------------------
// K5: build We_n[j,:] = sum_{m in seg(j)} We_m[m,:]/(c_m+1) + added[j]*We_m[nn_n[j],:]/(c_m+1)
//     and denom[j] = max(cnt+added, 1). One wave per j, lane = column.
__global__ __launch_bounds__(256) void k_wen(
        const float* __restrict__ We_m, const int* __restrict__ nn_n,
        const int* __restrict__ added, const int* __restrict__ c_m,
        const int* __restrict__ cnt, const int* __restrict__ offs,
        const int* __restrict__ list,
        float* __restrict__ We_n, float* __restrict__ denom) {
    int gid = blockIdx.x * 256 + threadIdx.x;
    int j = gid >> 6;
    int lane = gid & 63;
    if (j >= N_) return;
    int c = cnt[j], o = offs[j], a = added[j];
    float acc = 0.f;
    for (int q = 0; q < c; q++) {
        int m = list[o + q];
        float sc = 1.0f / (float)(c_m[m] + 1);
        acc += We_m[m * 64 + lane] * sc;
    }
    if (a) {
        int m = nn_n[j];
        float sc = 1.0f / (float)(c_m[m] + 1);
        acc += We_m[m * 64 + lane] * sc;
    }
    We_n[j * 64 + lane] = acc;
    if (lane == 0) denom[j] = fmaxf((float)(c + a), 1.0f);
}

// ---------------------------------------------------------------------------
// K6: encode partial GEMM. z[b,l] = sum_n x[b,n]*We_n[n,l].
// Block processes 64-n chunks (grid-stride); x tile staged in LDS; per-thread
// acc holds 16 (b,l) slots: thread t -> l = t&63, b in [wv*16, wv*16+16).
__global__ __launch_bounds__(256) void k_encode(const float* __restrict__ x,
        const float* __restrict__ We_n, float* __restrict__ zpart) {
    __shared__ float xt[64][68];          // xt[jj][b], padded for banks + 16B align
    int t = threadIdx.x;
    int wv = t >> 6, lane = t & 63;
    float acc[16];
#pragma unroll
    for (int i = 0; i < 16; i++) acc[i] = 0.f;

    for (int c = blockIdx.x; c < NCHUNK; c += ENC_GRID) {
        int n0 = c * 64;
        __syncthreads();
#pragma unroll
        for (int r = 0; r < 16; r++) {
            int idx = r * 256 + t;
            int bb = idx >> 6, jj = idx & 63;
            int n = n0 + jj;
            xt[jj][bb] = (n < N_) ? x[bb * N_ + n] : 0.f;
        }
        __syncthreads();
        int jmax = (N_ - n0 < 64) ? (N_ - n0) : 64;
        for (int jj = 0; jj < jmax; jj++) {
            float wn = We_n[(n0 + jj) * 64 + lane];
            const float4* xr = (const float4*)(&xt[jj][wv * 16]);
            float4 a0 = xr[0], a1 = xr[1], a2 = xr[2], a3 = xr[3];
            acc[0]  += a0.x * wn;  acc[1]  += a0.y * wn;  acc[2]  += a0.z * wn;  acc[3]  += a0.w * wn;
            acc[4]  += a1.x * wn;  acc[5]  += a1.y * wn;  acc[6]  += a1.z * wn;  acc[7]  += a1.w * wn;
            acc[8]  += a2.x * wn;  acc[9]  += a2.y * wn;  acc[10] += a2.z * wn;  acc[11] += a2.w * wn;
            acc[12] += a3.x * wn;  acc[13] += a3.y * wn;  acc[14] += a3.z * wn;  acc[15] += a3.w * wn;
        }
    }
#pragma unroll
    for (int i = 0; i < 16; i++)
        zpart[blockIdx.x * 4096 + (wv * 16 + i) * 64 + lane] = acc[i];
}

// K7: reduce z partials (512 x 4096 -> 4096).
__global__ void k_zreduce(const float* __restrict__ zpart, float* __restrict__ z) {
    int slot = blockIdx.x * 256 + threadIdx.x;   // 16 blocks x 256
    float s = 0.f;
    for (int k = 0; k < ENC_GRID; k++) s += zpart[k * 4096 + slot];
    z[slot] = s;
}

// ---------------------------------------------------------------------------
// K8: P[m,b] = sum_l (z[b,l]+be[l]) * Wd_m[l,m] + bd_m[m].  P layout [S][64].
// Wd_m read coalesced (thread = m); z2 broadcast from LDS.
__global__ __launch_bounds__(256) void k_pmat(
        const float* __restrict__ Wd_m, const float* __restrict__ bd_m,
        const float* __restrict__ z, const float* __restrict__ be_m,
        float* __restrict__ P) {
    __shared__ float z2[64][68];   // z2[l][b] = z[b*64+l] + be[l]
    int t = threadIdx.x;
#pragma unroll
    for (int k = 0; k < 16; k++) {
        int idx = k * 256 + t;
        int b = idx >> 6, l = idx & 63;
        z2[l][b] = z[idx] + be_m[l];
    }
    __syncthreads();
    int m = blockIdx.x * 256 + t;
    if (m >= S_) return;
    float bd = bd_m[m];
    float acc[64];
#pragma unroll
    for (int b = 0; b < 64; b++) acc[b] = bd;
    for (int l = 0; l < 64; l++) {
        float w = Wd_m[l * S_ + m];
        const float4* zr = (const float4*)(&z2[l][0]);
#pragma unroll
        for (int q = 0; q < 16; q++) {
            float4 v = zr[q];
            acc[q * 4 + 0] += v.x * w;
            acc[q * 4 + 1] += v.y * w;
            acc[q * 4 + 2] += v.z * w;
            acc[q * 4 + 3] += v.w * w;
        }
    }
    float4* Pv = (float4*)(&P[(size_t)m * 64]);
#pragma unroll
    for (int q = 0; q < 16; q++)
        Pv[q] = make_float4(acc[q * 4 + 0], acc[q * 4 + 1], acc[q * 4 + 2], acc[q * 4 + 3]);
}

// ---------------------------------------------------------------------------
// K9: out[b,j] = (sum_{m in seg(j)} P[m,b] + added[j]*P[nn_n[j],b]) / denom[j].
// One wave per j (lane = b); 64-j tile buffered in LDS; coalesced out writes.
__global__ __launch_bounds__(256) void k_decode(const float* __restrict__ P,
        const int* __restrict__ cnt, const int* __restrict__ offs,
        const int* __restrict__ list, const int* __restrict__ added,
        const int* __restrict__ nn_n, const float* __restrict__ denom,
        float* __restrict__ out) {
    __shared__ float tile[64][65];
    int t = threadIdx.x;
    int wv = t >> 6, lane = t & 63;
    int j0 = blockIdx.x * 64;
    for (int k = 0; k < 16; k++) {
        int jj = k * 4 + wv;
        int j = j0 + jj;
        float acc = 0.f;
        if (j < N_) {
            int c = cnt[j], o = offs[j];
            for (int q = 0; q < c; q++) {
                int m = list[o + q];
                acc += P[(size_t)m * 64 + lane];
            }
            if (added[j]) acc += P[(size_t)nn_n[j] * 64 + lane];
            acc *= (1.0f / denom[j]);
        }
        tile[jj][lane] = acc;
    }
    __syncthreads();
#pragma unroll
    for (int r = 0; r < 16; r++) {
        int b = r * 4 + wv;
        int j = j0 + lane;
        if (j < N_) out[(size_t)b * N_ + j] = tile[lane][b];
    }
}

// ---------------------------------------------------------------------------
extern "C" void kernel_launch(void* const* d_in, const int* in_sizes, int n_in,
                              void* d_out, int out_size, void* d_ws, size_t ws_size,
                              hipStream_t stream) {
    const float* We_m = (const float*)d_in[0];
    const float* be_m = (const float*)d_in[1];
    const float* Wd_m = (const float*)d_in[2];
    const float* bd_m = (const float*)d_in[3];
    const float* x    = (const float*)d_in[4];
    const int*   nn_n = (const int*)d_in[5];
    const int*   nn_m = (const int*)d_in[6];
    float* out = (float*)d_out;
    char* ws = (char*)d_ws;

    // Workspace layout (byte offsets). Region 0 holds We_n [N,64] during the
    // encode phase, then is reused for P [S,64] in the decode phase.
    float* We_n  = (float*)(ws + 0);           // 64,000,000 B
    float* P     = (float*)(ws + 0);           // 51,200,000 B (aliases We_n; phase-ordered)
    int*   c_m   = (int*)(ws + 64000000);      //    800,000 B (zeroed)
    int*   cnt   = (int*)(ws + 64800000);      //  1,000,000 B (zeroed)
    int*   fill  = (int*)(ws + 65800000);      //  1,000,000 B (zeroed)
    int*   added = (int*)(ws + 66800000);      //  1,000,000 B
    int*   offs  = (int*)(ws + 67800000);      //  1,000,000 B
    int*   list  = (int*)(ws + 68800000);      //    800,000 B
    float* denom = (float*)(ws + 69600000);    //  1,000,000 B
    float* zpart = (float*)(ws + 70600000);    //  8,388,608 B (512*4096*4)
    float* z     = (float*)(ws + 78988608);    //     16,384 B
    int*   bsum  = (int*)(ws + 79004992);      //      4,096 B
    // total ~79.0 MB

    hipMemsetAsync(ws + 64000000, 0, 2800000, stream);   // c_m, cnt, fill

    k_added_counts<<<977, 256, 0, stream>>>(nn_n, nn_m, added, c_m, cnt);
    k_scan_blocksum<<<245, 256, 0, stream>>>(cnt, bsum);
    k_scan_apply<<<245, 256, 0, stream>>>(cnt, bsum, offs);
    k_fill<<<782, 256, 0, stream>>>(nn_m, offs, fill, list);
    k_wen<<<62500, 256, 0, stream>>>(We_m, nn_n, added, c_m, cnt, offs, list, We_n, denom);
    k_encode<<<ENC_GRID, 256, 0, stream>>>(x, We_n, zpart);
    k_zreduce<<<16, 256, 0, stream>>>(zpart, z);
    k_pmat<<<782, 256, 0, stream>>>(Wd_m, bd_m, z, be_m, P);
    k_decode<<<3907, 256, 0, stream>>>(P, cnt, offs, list, added, nn_n, denom, out);
}

// Round 2
// 523.382 us; speedup vs baseline: 1.1235x; 1.1235x over previous
//
#include <hip/hip_runtime.h>

// Problem constants (match reference)
constexpr int S_ = 200000;   // master nodes
constexpr int N_ = 250000;   // new nodes
// L = B = 64

constexpr int ENC_GRID = 1024;
constexpr int NCHUNK   = (N_ + 63) / 64;   // 3907

// ---------------------------------------------------------------------------
// K1: added[n] = (nn_m[nn_n[n]] != n); c_m histogram (added only, over nn_n);
//     ecnt[j] = #masters with nn_m=j  +  added[j]  (extended segment size).
__global__ void k_added_counts(const int* __restrict__ nn_n, const int* __restrict__ nn_m,
                               int* __restrict__ added, int* __restrict__ c_m,
                               int* __restrict__ ecnt) {
    int i = blockIdx.x * 256 + threadIdx.x;
    if (i < N_) {
        int m = nn_n[i];
        int a = (nn_m[m] != i) ? 1 : 0;
        added[i] = a;
        if (a) {
            atomicAdd(&c_m[m], 1);
            atomicAdd(&ecnt[i], 1);
        }
    }
    if (i < S_) {
        atomicAdd(&ecnt[nn_m[i]], 1);
    }
}

// ---------------------------------------------------------------------------
// K2: per-block sums of ecnt (1024 elements / block) for the exclusive scan.
__global__ void k_scan_blocksum(const int* __restrict__ ecnt, int* __restrict__ bsum) {
    __shared__ int sd[256];
    int b = blockIdx.x, t = threadIdx.x;
    int base = b * 1024 + t * 4;
    int s = 0;
#pragma unroll
    for (int k = 0; k < 4; k++) { int idx = base + k; if (idx < N_) s += ecnt[idx]; }
    sd[t] = s;
    __syncthreads();
    for (int off = 128; off > 0; off >>= 1) {
        if (t < off) sd[t] += sd[t + off];
        __syncthreads();
    }
    if (t == 0) bsum[b] = sd[0];
}

// K3: exclusive scan -> offs.
__global__ void k_scan_apply(const int* __restrict__ ecnt, const int* __restrict__ bsum,
                             int* __restrict__ offs) {
    __shared__ int sd[256];
    __shared__ int sp[256];
    int b = blockIdx.x, t = threadIdx.x;
    sp[t] = (t < b) ? bsum[t] : 0;
    __syncthreads();
    for (int off = 128; off > 0; off >>= 1) {
        if (t < off) sp[t] += sp[t + off];
        __syncthreads();
    }
    int prev = sp[0];

    int base = b * 1024 + t * 4;
    int v[4]; int s = 0;
#pragma unroll
    for (int k = 0; k < 4; k++) { int idx = base + k; v[k] = (idx < N_) ? ecnt[idx] : 0; s += v[k]; }
    sd[t] = s;
    __syncthreads();
    for (int off = 1; off < 256; off <<= 1) {
        int xv = (t >= off) ? sd[t - off] : 0;
        __syncthreads();
        sd[t] += xv;
        __syncthreads();
    }
    int run = prev + sd[t] - s;
#pragma unroll
    for (int k = 0; k < 4; k++) {
        int idx = base + k;
        if (idx < N_) offs[idx] = run;
        run += v[k];
    }
}

// K4: extended CSR fill — masters (nn_m inverse) plus the added contributor
//     nn_n[j] appended to segment j.
__global__ void k_fill(const int* __restrict__ nn_m, const int* __restrict__ nn_n,
                       const int* __restrict__ added, const int* __restrict__ offs,
                       int* __restrict__ fill, int* __restrict__ elist) {
    int i = blockIdx.x * 256 + threadIdx.x;
    if (i < S_) {
        int j = nn_m[i];
        int p = atomicAdd(&fill[j], 1);
        elist[offs[j] + p] = i;
    }
    if (i < N_ && added[i]) {
        int p = atomicAdd(&fill[i], 1);
        elist[offs[i] + p] = nn_n[i];
    }
}

// ---------------------------------------------------------------------------
// K5: We_n[j,:] = sum_{m in elist(j)} We_m[m,:] / (c_m[m]+1).
// One wave per j, lane = column (coalesced 256B row reads).
__global__ __launch_bounds__(256) void k_wen(
        const float* __restrict__ We_m, const int* __restrict__ c_m,
        const int* __restrict__ ecnt, const int* __restrict__ offs,
        const int* __restrict__ elist, float* __restrict__ We_n) {
    int gid = blockIdx.x * 256 + threadIdx.x;
    int j = gid >> 6;
    int lane = gid & 63;
    if (j >= N_) return;
    int c = ecnt[j], o = offs[j];
    float acc = 0.f;
    for (int q = 0; q < c; q++) {
        int m = elist[o + q];
        float sc = 1.0f / (float)(c_m[m] + 1);
        acc += We_m[(size_t)m * 64 + lane] * sc;
    }
    We_n[(size_t)j * 64 + lane] = acc;
}

// ---------------------------------------------------------------------------
// K6: encode GEMM z[b,l] = sum_n x[b,n]*We_n[n,l].
// lane = b; wave wv accumulates l in [wv*16, wv*16+16).
// x chunk staged in LDS (conflict-free b32 reads, per-lane distinct).
// We_n fragment read via uniform address -> scalar s_load, SGPR fmac operand.
// Epilogue: atomicAdd into 64-row staging zp2 (16-way contention).
__global__ __launch_bounds__(256) void k_encode(const float* __restrict__ x,
        const float* __restrict__ We_n, float* __restrict__ zp2) {
    __shared__ float xt[64 * 65];         // xt[jj*65 + b]
    int t = threadIdx.x;
    int lane = t & 63;                     // b
    int wvu = __builtin_amdgcn_readfirstlane(t >> 6);  // uniform wave id
    float acc[16];
#pragma unroll
    for (int i = 0; i < 16; i++) acc[i] = 0.f;

    for (int c = blockIdx.x; c < NCHUNK; c += ENC_GRID) {
        int n0 = c * 64;
        __syncthreads();
#pragma unroll
        for (int r = 0; r < 16; r++) {
            int idx = r * 256 + t;
            int bb = idx >> 6, jj = idx & 63;          // lanes -> consecutive jj
            int n = n0 + jj;
            xt[jj * 65 + bb] = (n < N_) ? x[(size_t)bb * N_ + n] : 0.f;
        }
        __syncthreads();
        int jmax = (N_ - n0 < 64) ? (N_ - n0) : 64;
        const float* wbase = We_n + (size_t)n0 * 64 + wvu * 16;
        for (int jj = 0; jj < jmax; jj++) {
            float xv = xt[jj * 65 + lane];             // per-lane distinct, no conflict
            const float* w = wbase + jj * 64;          // uniform -> s_load
#pragma unroll
            for (int i = 0; i < 16; i++) acc[i] += xv * w[i];
        }
    }
    int row = blockIdx.x & 63;
#pragma unroll
    for (int i = 0; i < 16; i++) {
        int slot = (wvu * 16 + i) * 64 + lane;         // l*64 + b
        atomicAdd(&zp2[row * 4096 + slot], acc[i]);
    }
}

// K7: z2g[l*64+b] = sum_rows zp2 + be[l].
__global__ void k_zred(const float* __restrict__ zp2, const float* __restrict__ be_m,
                       float* __restrict__ z2g) {
    int slot = blockIdx.x * 256 + threadIdx.x;   // 16 blocks x 256
    float s = 0.f;
    for (int r = 0; r < 64; r++) s += zp2[r * 4096 + slot];
    z2g[slot] = s + be_m[slot >> 6];
}

// ---------------------------------------------------------------------------
// K8: P[m,b] = sum_l z2g[l*64+b] * Wd_m[l,m] + bd_m[m].  P layout [S][64].
// Wd_m read coalesced (thread = m); z2g via uniform s_loads (no LDS).
__global__ __launch_bounds__(256) void k_pmat(
        const float* __restrict__ Wd_m, const float* __restrict__ bd_m,
        const float* __restrict__ z2g, float* __restrict__ P) {
    int m = blockIdx.x * 256 + threadIdx.x;
    if (m >= S_) return;
    float bd = bd_m[m];
    float acc[64];
#pragma unroll
    for (int b = 0; b < 64; b++) acc[b] = bd;
    for (int l = 0; l < 64; l++) {
        float w = Wd_m[(size_t)l * S_ + m];            // coalesced
        const float* zr = z2g + l * 64;                // uniform -> s_load
#pragma unroll
        for (int g = 0; g < 4; g++) {
#pragma unroll
            for (int q = 0; q < 16; q++)
                acc[g * 16 + q] += w * zr[g * 16 + q];
        }
    }
    float4* Pv = (float4*)(&P[(size_t)m * 64]);
#pragma unroll
    for (int q = 0; q < 16; q++)
        Pv[q] = make_float4(acc[q * 4 + 0], acc[q * 4 + 1], acc[q * 4 + 2], acc[q * 4 + 3]);
}

// ---------------------------------------------------------------------------
// K9: out[b,j] = (sum_{m in elist(j)} P[m,b]) / max(ecnt[j],1).
// One wave per j (lane = b); 64-j tile through LDS for coalesced out writes.
__global__ __launch_bounds__(256) void k_decode(const float* __restrict__ P,
        const int* __restrict__ ecnt, const int* __restrict__ offs,
        const int* __restrict__ elist, float* __restrict__ out) {
    __shared__ float tile[64][65];
    int t = threadIdx.x;
    int wv = t >> 6, lane = t & 63;
    int j0 = blockIdx.x * 64;
    for (int k = 0; k < 16; k++) {
        int jj = k * 4 + wv;
        int j = j0 + jj;
        float acc = 0.f;
        if (j < N_) {
            int c = ecnt[j], o = offs[j];
            for (int q = 0; q < c; q++) {
                int m = elist[o + q];
                acc += P[(size_t)m * 64 + lane];
            }
            int d = (c > 1) ? c : 1;
            acc *= (1.0f / (float)d);
        }
        tile[jj][lane] = acc;
    }
    __syncthreads();
#pragma unroll
    for (int r = 0; r < 16; r++) {
        int b = r * 4 + wv;
        int j = j0 + lane;
        if (j < N_) out[(size_t)b * N_ + j] = tile[lane][b];
    }
}

// ---------------------------------------------------------------------------
extern "C" void kernel_launch(void* const* d_in, const int* in_sizes, int n_in,
                              void* d_out, int out_size, void* d_ws, size_t ws_size,
                              hipStream_t stream) {
    const float* We_m = (const float*)d_in[0];
    const float* be_m = (const float*)d_in[1];
    const float* Wd_m = (const float*)d_in[2];
    const float* bd_m = (const float*)d_in[3];
    const float* x    = (const float*)d_in[4];
    const int*   nn_n = (const int*)d_in[5];
    const int*   nn_m = (const int*)d_in[6];
    float* out = (float*)d_out;
    char* ws = (char*)d_ws;

    // Workspace layout (byte offsets). Region 0 holds We_n [N,64] during the
    // encode phase, then is reused for P [S,64] in the decode phase.
    float* We_n  = (float*)(ws + 0);           // 64,000,000 B
    float* P     = (float*)(ws + 0);           // 51,200,000 B (aliases We_n; phase-ordered)
    int*   c_m   = (int*)(ws + 64000000);      //    800,000 B (zeroed)
    int*   ecnt  = (int*)(ws + 64800000);      //  1,000,000 B (zeroed)
    int*   fill  = (int*)(ws + 65800000);      //  1,000,000 B (zeroed)
    int*   added = (int*)(ws + 66800000);      //  1,000,000 B
    int*   offs  = (int*)(ws + 67800000);      //  1,000,000 B
    int*   elist = (int*)(ws + 68800000);      //  2,000,000 B (<= (S+N)*4 = 1.8 MB)
    float* zp2   = (float*)(ws + 70800000);    //  1,048,576 B (64 x 4096, zeroed)
    float* z2g   = (float*)(ws + 71848576);    //     16,384 B
    int*   bsum  = (int*)(ws + 71864960);      //      1,024 B
    // total ~71.9 MB

    hipMemsetAsync(ws + 64000000, 0, 2800000, stream);   // c_m, ecnt, fill
    hipMemsetAsync(zp2, 0, 1048576, stream);             // zp2

    k_added_counts<<<977, 256, 0, stream>>>(nn_n, nn_m, added, c_m, ecnt);
    k_scan_blocksum<<<245, 256, 0, stream>>>(ecnt, bsum);
    k_scan_apply<<<245, 256, 0, stream>>>(ecnt, bsum, offs);
    k_fill<<<977, 256, 0, stream>>>(nn_m, nn_n, added, offs, fill, elist);
    k_wen<<<62500, 256, 0, stream>>>(We_m, c_m, ecnt, offs, elist, We_n);
    k_encode<<<ENC_GRID, 256, 0, stream>>>(x, We_n, zp2);
    k_zred<<<16, 256, 0, stream>>>(zp2, be_m, z2g);
    k_pmat<<<782, 256, 0, stream>>>(Wd_m, bd_m, z2g, P);
    k_decode<<<3907, 256, 0, stream>>>(P, ecnt, offs, elist, out);
}

// Round 3
// 467.975 us; speedup vs baseline: 1.2565x; 1.1184x over previous
//
#include <hip/hip_runtime.h>

// Problem constants (match reference)
constexpr int S_ = 200000;   // master nodes
constexpr int N_ = 250000;   // new nodes
// L = B = 64

constexpr int ENC_GRID = 1024;
constexpr int NCHUNK   = (N_ + 63) / 64;   // 3907

// ---------------------------------------------------------------------------
// K1: added[n] = (nn_m[nn_n[n]] != n); c_m histogram (added only, over nn_n);
//     ecnt[j] = #masters with nn_m=j  +  added[j]  (extended segment size).
__global__ void k_added_counts(const int* __restrict__ nn_n, const int* __restrict__ nn_m,
                               int* __restrict__ added, int* __restrict__ c_m,
                               int* __restrict__ ecnt) {
    int i = blockIdx.x * 256 + threadIdx.x;
    if (i < N_) {
        int m = nn_n[i];
        int a = (nn_m[m] != i) ? 1 : 0;
        added[i] = a;
        if (a) {
            atomicAdd(&c_m[m], 1);
            atomicAdd(&ecnt[i], 1);
        }
    }
    if (i < S_) {
        atomicAdd(&ecnt[nn_m[i]], 1);
    }
}

// ---------------------------------------------------------------------------
// K2: per-block sums of ecnt (1024 elements / block) for the exclusive scan.
__global__ void k_scan_blocksum(const int* __restrict__ ecnt, int* __restrict__ bsum) {
    __shared__ int sd[256];
    int b = blockIdx.x, t = threadIdx.x;
    int base = b * 1024 + t * 4;
    int s = 0;
#pragma unroll
    for (int k = 0; k < 4; k++) { int idx = base + k; if (idx < N_) s += ecnt[idx]; }
    sd[t] = s;
    __syncthreads();
    for (int off = 128; off > 0; off >>= 1) {
        if (t < off) sd[t] += sd[t + off];
        __syncthreads();
    }
    if (t == 0) bsum[b] = sd[0];
}

// K3: exclusive scan -> offs.
__global__ void k_scan_apply(const int* __restrict__ ecnt, const int* __restrict__ bsum,
                             int* __restrict__ offs) {
    __shared__ int sd[256];
    __shared__ int sp[256];
    int b = blockIdx.x, t = threadIdx.x;
    sp[t] = (t < b) ? bsum[t] : 0;
    __syncthreads();
    for (int off = 128; off > 0; off >>= 1) {
        if (t < off) sp[t] += sp[t + off];
        __syncthreads();
    }
    int prev = sp[0];

    int base = b * 1024 + t * 4;
    int v[4]; int s = 0;
#pragma unroll
    for (int k = 0; k < 4; k++) { int idx = base + k; v[k] = (idx < N_) ? ecnt[idx] : 0; s += v[k]; }
    sd[t] = s;
    __syncthreads();
    for (int off = 1; off < 256; off <<= 1) {
        int xv = (t >= off) ? sd[t - off] : 0;
        __syncthreads();
        sd[t] += xv;
        __syncthreads();
    }
    int run = prev + sd[t] - s;
#pragma unroll
    for (int k = 0; k < 4; k++) {
        int idx = base + k;
        if (idx < N_) offs[idx] = run;
        run += v[k];
    }
}

// K4: extended CSR fill — masters (nn_m inverse) plus the added contributor
//     nn_n[j] appended to segment j.
__global__ void k_fill(const int* __restrict__ nn_m, const int* __restrict__ nn_n,
                       const int* __restrict__ added, const int* __restrict__ offs,
                       int* __restrict__ fill, int* __restrict__ elist) {
    int i = blockIdx.x * 256 + threadIdx.x;
    if (i < S_) {
        int j = nn_m[i];
        int p = atomicAdd(&fill[j], 1);
        elist[offs[j] + p] = i;
    }
    if (i < N_ && added[i]) {
        int p = atomicAdd(&fill[i], 1);
        elist[offs[i] + p] = nn_n[i];
    }
}

// ---------------------------------------------------------------------------
// K5: We_n[j,:] = sum_{m in elist(j)} We_m[m,:] / (c_m[m]+1).
// One wave serves FOUR segments concurrently (4 gathers in flight -> 4x MLP).
// lane = column; all control flow is wave-uniform.
__global__ __launch_bounds__(256) void k_wen(
        const float* __restrict__ We_m, const int* __restrict__ c_m,
        const int* __restrict__ ecnt, const int* __restrict__ offs,
        const int* __restrict__ elist, float* __restrict__ We_n) {
    int t = threadIdx.x;
    int lane = t & 63;
    int wid = blockIdx.x * 4 + (t >> 6);
    int jb = wid * 4;                     // 4 segments per wave
    if (jb >= N_) return;
    int c[4], o[4];
    float acc[4];
#pragma unroll
    for (int s = 0; s < 4; s++) {
        int j = jb + s;
        bool v = (j < N_);
        c[s] = v ? ecnt[j] : 0;
        o[s] = v ? offs[j] : 0;
        acc[s] = 0.f;
    }
    int cmax = max(max(c[0], c[1]), max(c[2], c[3]));
    for (int q = 0; q < cmax; q++) {
        int mm[4];
#pragma unroll
        for (int s = 0; s < 4; s++)
            mm[s] = (q < c[s]) ? elist[o[s] + q] : -1;   // 4 independent broadcast loads
        float row[4], sc[4];
#pragma unroll
        for (int s = 0; s < 4; s++) {
            if (mm[s] >= 0) {
                row[s] = We_m[(size_t)mm[s] * 64 + lane]; // 4 independent row gathers
                sc[s]  = 1.0f / (float)(c_m[mm[s]] + 1);
            }
        }
#pragma unroll
        for (int s = 0; s < 4; s++)
            if (mm[s] >= 0) acc[s] += row[s] * sc[s];
    }
#pragma unroll
    for (int s = 0; s < 4; s++) {
        int j = jb + s;
        if (j < N_) We_n[(size_t)j * 64 + lane] = acc[s];
    }
}

// ---------------------------------------------------------------------------
// K6: encode GEMM z[b,l] = sum_n x[b,n]*We_n[n,l].
// lane = b; wave wv accumulates l in [wv*16, wv*16+16).
// x chunk staged in LDS (conflict-free b32 reads, per-lane distinct).
// We_n fragment read via uniform address -> scalar s_load, SGPR fmac operand.
// Epilogue: atomicAdd into 64-row staging zp2 (16-way contention).
__global__ __launch_bounds__(256) void k_encode(const float* __restrict__ x,
        const float* __restrict__ We_n, float* __restrict__ zp2) {
    __shared__ float xt[64 * 65];         // xt[jj*65 + b]
    int t = threadIdx.x;
    int lane = t & 63;                     // b
    int wvu = __builtin_amdgcn_readfirstlane(t >> 6);  // uniform wave id
    float acc[16];
#pragma unroll
    for (int i = 0; i < 16; i++) acc[i] = 0.f;

    for (int c = blockIdx.x; c < NCHUNK; c += ENC_GRID) {
        int n0 = c * 64;
        __syncthreads();
#pragma unroll
        for (int r = 0; r < 16; r++) {
            int idx = r * 256 + t;
            int bb = idx >> 6, jj = idx & 63;          // lanes -> consecutive jj
            int n = n0 + jj;
            xt[jj * 65 + bb] = (n < N_) ? x[(size_t)bb * N_ + n] : 0.f;
        }
        __syncthreads();
        int jmax = (N_ - n0 < 64) ? (N_ - n0) : 64;
        const float* wbase = We_n + (size_t)n0 * 64 + wvu * 16;
        for (int jj = 0; jj < jmax; jj++) {
            float xv = xt[jj * 65 + lane];             // per-lane distinct, no conflict
            const float* w = wbase + jj * 64;          // uniform -> s_load
#pragma unroll
            for (int i = 0; i < 16; i++) acc[i] += xv * w[i];
        }
    }
    int row = blockIdx.x & 63;
#pragma unroll
    for (int i = 0; i < 16; i++) {
        int slot = (wvu * 16 + i) * 64 + lane;         // l*64 + b
        atomicAdd(&zp2[row * 4096 + slot], acc[i]);
    }
}

// K7: z2g[l*64+b] = sum_rows zp2 + be[l].
__global__ void k_zred(const float* __restrict__ zp2, const float* __restrict__ be_m,
                       float* __restrict__ z2g) {
    int slot = blockIdx.x * 256 + threadIdx.x;   // 16 blocks x 256
    float s = 0.f;
    for (int r = 0; r < 64; r++) s += zp2[r * 4096 + slot];
    z2g[slot] = s + be_m[slot >> 6];
}

// ---------------------------------------------------------------------------
// K8: P[m,b] = sum_l z2g[l*64+b] * Wd_m[l,m] + bd_m[m].  P layout [S][64].
// Wd_m read coalesced (thread = m); z2g via uniform s_loads (no LDS).
__global__ __launch_bounds__(256) void k_pmat(
        const float* __restrict__ Wd_m, const float* __restrict__ bd_m,
        const float* __restrict__ z2g, float* __restrict__ P) {
    int m = blockIdx.x * 256 + threadIdx.x;
    if (m >= S_) return;
    float bd = bd_m[m];
    float acc[64];
#pragma unroll
    for (int b = 0; b < 64; b++) acc[b] = bd;
    for (int l = 0; l < 64; l++) {
        float w = Wd_m[(size_t)l * S_ + m];            // coalesced
        const float* zr = z2g + l * 64;                // uniform -> s_load
#pragma unroll
        for (int g = 0; g < 4; g++) {
#pragma unroll
            for (int q = 0; q < 16; q++)
                acc[g * 16 + q] += w * zr[g * 16 + q];
        }
    }
    float4* Pv = (float4*)(&P[(size_t)m * 64]);
#pragma unroll
    for (int q = 0; q < 16; q++)
        Pv[q] = make_float4(acc[q * 4 + 0], acc[q * 4 + 1], acc[q * 4 + 2], acc[q * 4 + 3]);
}

// ---------------------------------------------------------------------------
// K9: out[b,j] = (sum_{m in elist(j)} P[m,b]) / max(ecnt[j],1).
// Wave serves its 16 jj's in 4 groups of 4 concurrent segments (4x MLP).
// lane = b; 64-j tile through LDS for coalesced out writes.
__global__ __launch_bounds__(256) void k_decode(const float* __restrict__ P,
        const int* __restrict__ ecnt, const int* __restrict__ offs,
        const int* __restrict__ elist, float* __restrict__ out) {
    __shared__ float tile[64][65];
    int t = threadIdx.x;
    int wv = t >> 6, lane = t & 63;
    int j0 = blockIdx.x * 64;
    for (int g = 0; g < 4; g++) {
        int jjb = wv * 16 + g * 4;
        int c[4], o[4];
        float acc[4];
#pragma unroll
        for (int s = 0; s < 4; s++) {
            int j = j0 + jjb + s;
            bool v = (j < N_);
            c[s] = v ? ecnt[j] : 0;
            o[s] = v ? offs[j] : 0;
            acc[s] = 0.f;
        }
        int cmax = max(max(c[0], c[1]), max(c[2], c[3]));
        for (int q = 0; q < cmax; q++) {
            int mm[4];
#pragma unroll
            for (int s = 0; s < 4; s++)
                mm[s] = (q < c[s]) ? elist[o[s] + q] : -1;  // 4 independent broadcast loads
#pragma unroll
            for (int s = 0; s < 4; s++)
                if (mm[s] >= 0) acc[s] += P[(size_t)mm[s] * 64 + lane]; // 4 row gathers in flight
        }
#pragma unroll
        for (int s = 0; s < 4; s++) {
            int cc = (c[s] > 1) ? c[s] : 1;
            tile[jjb + s][lane] = acc[s] * (1.0f / (float)cc);
        }
    }
    __syncthreads();
#pragma unroll
    for (int r = 0; r < 16; r++) {
        int b = r * 4 + wv;
        int j = j0 + lane;
        if (j < N_) out[(size_t)b * N_ + j] = tile[lane][b];
    }
}

// ---------------------------------------------------------------------------
extern "C" void kernel_launch(void* const* d_in, const int* in_sizes, int n_in,
                              void* d_out, int out_size, void* d_ws, size_t ws_size,
                              hipStream_t stream) {
    const float* We_m = (const float*)d_in[0];
    const float* be_m = (const float*)d_in[1];
    const float* Wd_m = (const float*)d_in[2];
    const float* bd_m = (const float*)d_in[3];
    const float* x    = (const float*)d_in[4];
    const int*   nn_n = (const int*)d_in[5];
    const int*   nn_m = (const int*)d_in[6];
    float* out = (float*)d_out;
    char* ws = (char*)d_ws;

    // Workspace layout (byte offsets). Region 0 holds We_n [N,64] during the
    // encode phase, then is reused for P [S,64] in the decode phase.
    float* We_n  = (float*)(ws + 0);           // 64,000,000 B
    float* P     = (float*)(ws + 0);           // 51,200,000 B (aliases We_n; phase-ordered)
    int*   c_m   = (int*)(ws + 64000000);      //    800,000 B (zeroed)
    int*   ecnt  = (int*)(ws + 64800000);      //  1,000,000 B (zeroed)
    int*   fill  = (int*)(ws + 65800000);      //  1,000,000 B (zeroed)
    int*   added = (int*)(ws + 66800000);      //  1,000,000 B
    int*   offs  = (int*)(ws + 67800000);      //  1,000,000 B
    int*   elist = (int*)(ws + 68800000);      //  2,000,000 B (<= (S+N)*4 = 1.8 MB)
    float* zp2   = (float*)(ws + 70800000);    //  1,048,576 B (64 x 4096, zeroed)
    float* z2g   = (float*)(ws + 71848576);    //     16,384 B
    int*   bsum  = (int*)(ws + 71864960);      //      1,024 B
    // total ~71.9 MB

    hipMemsetAsync(ws + 64000000, 0, 2800000, stream);   // c_m, ecnt, fill
    hipMemsetAsync(zp2, 0, 1048576, stream);             // zp2

    k_added_counts<<<977, 256, 0, stream>>>(nn_n, nn_m, added, c_m, ecnt);
    k_scan_blocksum<<<245, 256, 0, stream>>>(ecnt, bsum);
    k_scan_apply<<<245, 256, 0, stream>>>(ecnt, bsum, offs);
    k_fill<<<977, 256, 0, stream>>>(nn_m, nn_n, added, offs, fill, elist);
    k_wen<<<15625, 256, 0, stream>>>(We_m, c_m, ecnt, offs, elist, We_n);
    k_encode<<<ENC_GRID, 256, 0, stream>>>(x, We_n, zp2);
    k_zred<<<16, 256, 0, stream>>>(zp2, be_m, z2g);
    k_pmat<<<782, 256, 0, stream>>>(Wd_m, bd_m, z2g, P);
    k_decode<<<3907, 256, 0, stream>>>(P, ecnt, offs, elist, out);
}